// Round 5
// baseline (355.549 us; speedup 1.0000x reference)
//
#include <hip/hip_runtime.h>

typedef unsigned short u16;
using u16x4  = __attribute__((ext_vector_type(4))) unsigned short;
using u16x8  = __attribute__((ext_vector_type(8))) unsigned short;
using bf16x8 = __attribute__((ext_vector_type(8))) short;
using f32x4  = __attribute__((ext_vector_type(4))) float;

// ---------- helpers ----------
__device__ __forceinline__ u16 f2bf(float f) {
  union { float f; unsigned u; } v; v.f = f;
  unsigned r = v.u + 0x7FFFu + ((v.u >> 16) & 1u);  // RNE (inputs bounded, no NaN)
  return (u16)(r >> 16);
}

// ---------- pre-pass 1: x fp32 -> bf16 ----------
// x is 2048*256 fp32 = 131072 float4 -> EXACTLY 512 blocks of 256 threads.
__global__ void convert_x_k(const float* __restrict__ in, u16* __restrict__ out) {
  int i = blockIdx.x * 256 + threadIdx.x;
  float4 v = ((const float4*)in)[i];
  u16x4 u;
  u.x = f2bf(v.x); u.y = f2bf(v.y); u.z = f2bf(v.z); u.w = f2bf(v.w);
  ((u16x4*)out)[i] = u;
}

// ---------- pre-pass 2: both W tensors [mat][i][h] fp32 -> blocked bf16 [mat][i/32][h][32] ----------
__global__ __launch_bounds__(256) void transpose_w2_k(
    const float* __restrict__ W1, const float* __restrict__ W2,
    u16* __restrict__ w1t, u16* __restrict__ w2t) {
  __shared__ float tile[64][65];
  const int bid = blockIdx.x;
  const int mat = bid >> 4;
  const int tl  = bid & 15;
  const int i0 = (tl >> 2) * 64, h0 = (tl & 3) * 64;
  const float* src = (mat < 256) ? (W1 + mat * 65536) : (W2 + (mat - 256) * 65536);
  u16*       dst   = (mat < 256) ? (w1t + mat * 65536) : (w2t + (mat - 256) * 65536);
  const int t = threadIdx.x;
#pragma unroll
  for (int j = 0; j < 4; ++j) {
    int lin = j * 256 + t;
    int row = lin >> 4, c4 = lin & 15;
    float4 v = *(const float4*)(src + (i0 + row) * 256 + h0 + c4 * 4);
    tile[row][c4 * 4 + 0] = v.x; tile[row][c4 * 4 + 1] = v.y;
    tile[row][c4 * 4 + 2] = v.z; tile[row][c4 * 4 + 3] = v.w;
  }
  __syncthreads();
  const int col = t >> 2;            // n = h0 + col
  const int kk  = (t & 3) * 8;
#pragma unroll
  for (int p = 0; p < 2; ++p) {      // two 32-wide k-chunks per 64-row tile
    u16x8 o;
#pragma unroll
    for (int jj = 0; jj < 8; ++jj)
      o[jj] = f2bf(tile[p * 32 + kk + jj][col]);
    *(u16x8*)(dst + ((i0 >> 5) + p) * 8192 + (h0 + col) * 32 + kk) = o;
  }
}

// ---------- main fused kernel ----------
// Block = (subcarrier c, 128-row batch tile). 512 threads = 8 waves, wave tile 64x64.
// B-fragments direct global->VGPR (L2-resident, XCD-affine). sH holds x then H1 in a
// stride-256 XOR-swizzled layout: element (row,col) lives at
//   row*256 + (((col>>3) ^ (row&7))<<3) + (col&7)     [u16 units]
// -> conflict-free b128 A-frag reads. K-loops fully unrolled, zero internal barriers.
// LDS 65.5K + 2K red -> 2 blocks/CU = 16 waves/CU.
__global__ __launch_bounds__(512, 4) void rf_main_k(
    const u16* __restrict__ xb, const u16* __restrict__ w1t, const u16* __restrict__ w2t,
    const float* __restrict__ b1, const float* __restrict__ b2,
    const float* __restrict__ w3, const float* __restrict__ b3,
    float* __restrict__ out) {
  __shared__ u16 sH[128 * 256];        // x-tile, then H1 (in place), swizzled
  __shared__ float red[512];           // 8 waves x 64 rows

  const int bid  = blockIdx.x;
  const int xcd  = bid & 7;
  const int j8   = bid >> 3;           // 0..511
  const int c    = xcd * 32 + (j8 >> 4);
  const int b0   = (j8 & 15) * 128;
  const int t    = threadIdx.x;
  const int lane = t & 63;
  const int w    = t >> 6;
  const int l15  = lane & 15;
  const int quad = lane >> 4;
  const int half = w >> 2;             // row half (0: rows 0-63, 1: rows 64-127)
  const int nw   = (w & 3) * 64;       // col base

  const u16* w1c = w1t + c * 65536;
  const u16* w2c = w2t + c * 65536;
  // B global per-lane offset: + ch*8192 + ni*512
  const int boff  = (nw + l15) * 32 + quad * 8;
  // A-frag swizzled LDS address: Abase + mi*4096 + ((ch ^ cxor)<<5)
  const int cxor  = (l15 >> 2) & 1;
  const int Abase = (half * 64 + l15) * 256 + ((quad ^ (l15 & 3)) << 3);

  f32x4  acc[4][4] = {};
  bf16x8 bA[4], bB[4];

#define LOADB(dst, base)                                        \
  { _Pragma("unroll")                                           \
    for (int _n = 0; _n < 4; ++_n)                              \
      dst[_n] = *(const bf16x8*)((base) + _n * 512); }

#define COMPUTE(bfr, ch)                                        \
  { bf16x8 _a[4];                                               \
    _Pragma("unroll")                                           \
    for (int _m = 0; _m < 4; ++_m)                              \
      _a[_m] = *(const bf16x8*)&sH[Abase + _m * 4096 + (((ch) ^ cxor) << 5)]; \
    _Pragma("unroll")                                           \
    for (int _m = 0; _m < 4; ++_m)                              \
      _Pragma("unroll")                                         \
      for (int _n = 0; _n < 4; ++_n)                            \
        acc[_m][_n] = __builtin_amdgcn_mfma_f32_16x16x32_bf16(_a[_m], bfr[_n], acc[_m][_n], 0, 0, 0); \
  }

  // prefetch W1 chunk 0 while staging x
  LOADB(bA, w1c + boff);

  // stage x-tile: 128 rows x 256 u16 -> swizzled sH (one time)
#pragma unroll
  for (int i = 0; i < 8; ++i) {
    int flat = i * 512 + t;
    int r = flat >> 5, s = flat & 31;          // s = 16B-block index in row
    u16x8 g = *(const u16x8*)(xb + (b0 + r) * 256 + s * 8);
    *(u16x8*)&sH[r * 256 + ((s ^ (r & 7)) << 3)] = g;
  }
  __syncthreads();

  // ========== Phase A: H1 = relu(x @ W1[c] + b1), barrier-free K-loop ==========
#pragma unroll
  for (int ch = 0; ch < 8; ch += 2) {
    LOADB(bB, w1c + (ch + 1) * 8192 + boff);
    COMPUTE(bA, ch);
    const u16* nxt = (ch == 6) ? (w2c + boff)                    // phase-B ch0 prefetch
                               : (w1c + (ch + 2) * 8192 + boff);
    LOADB(bA, nxt);
    COMPUTE(bB, ch + 1);
  }

  // Phase A epilogue: bias+relu -> bf16 H1, in place over x (swizzled writes)
  __syncthreads();                     // all x reads retired
#pragma unroll
  for (int ni = 0; ni < 4; ++ni) {
    int col  = nw + ni * 16 + l15;
    int cblk = col >> 3;               // no carry: nw+ni*16 is a multiple of 16
    float bias = b1[c * 256 + col];
#pragma unroll
    for (int mi = 0; mi < 4; ++mi)
#pragma unroll
      for (int r = 0; r < 4; ++r) {
        int row = half * 64 + mi * 16 + quad * 4 + r;
        int rw7 = (quad * 4 + r) & 7;
        float v = acc[mi][ni][r] + bias;
        v = v > 0.f ? v : 0.f;
        sH[row * 256 + ((cblk ^ rw7) << 3) + (col & 7)] = f2bf(v);
        acc[mi][ni][r] = 0.f;
      }
  }
  __syncthreads();                     // H1 published

  // ========== Phase B: relu(H1 @ W2[c] + b2) . W3, barrier-free K-loop ==========
#pragma unroll
  for (int ch = 0; ch < 8; ch += 2) {
    LOADB(bB, w2c + (ch + 1) * 8192 + boff);
    COMPUTE(bA, ch);
    if (ch < 6) LOADB(bA, w2c + (ch + 2) * 8192 + boff);
    COMPUTE(bB, ch + 1);
  }

  // Phase B epilogue: out = relu(acc + b2) . W3 + b3
  float part[16];
#pragma unroll
  for (int i = 0; i < 16; ++i) part[i] = 0.f;
#pragma unroll
  for (int ni = 0; ni < 4; ++ni) {
    int col = nw + ni * 16 + l15;
    float bias = b2[c * 256 + col];
    float w3v  = w3[c * 256 + col];
#pragma unroll
    for (int mi = 0; mi < 4; ++mi)
#pragma unroll
      for (int r = 0; r < 4; ++r) {
        float v = acc[mi][ni][r] + bias;
        v = v > 0.f ? v : 0.f;
        part[mi * 4 + r] += v * w3v;
      }
  }
#pragma unroll
  for (int m = 1; m < 16; m <<= 1)
#pragma unroll
    for (int i = 0; i < 16; ++i)
      part[i] += __shfl_xor(part[i], m, 64);

  if (l15 == 0) {
#pragma unroll
    for (int mi = 0; mi < 4; ++mi)
#pragma unroll
      for (int r = 0; r < 4; ++r)
        red[w * 64 + mi * 16 + quad * 4 + r] = part[mi * 4 + r];
  }
  __syncthreads();
  if (t < 128) {
    int hr = t >> 6, rr = t & 63;
    float v = red[(hr * 4 + 0) * 64 + rr] + red[(hr * 4 + 1) * 64 + rr] +
              red[(hr * 4 + 2) * 64 + rr] + red[(hr * 4 + 3) * 64 + rr] + b3[c];
    out[(b0 + t) * 256 + c] = v;
  }
#undef LOADB
#undef COMPUTE
}

// ---------- launcher ----------
extern "C" void kernel_launch(void* const* d_in, const int* in_sizes, int n_in,
                              void* d_out, int out_size, void* d_ws, size_t ws_size,
                              hipStream_t stream) {
  const float* x  = (const float*)d_in[0];
  const float* W1 = (const float*)d_in[1];
  const float* b1 = (const float*)d_in[2];
  const float* W2 = (const float*)d_in[3];
  const float* b2 = (const float*)d_in[4];
  const float* W3 = (const float*)d_in[5];
  const float* b3 = (const float*)d_in[6];
  float* out = (float*)d_out;

  char* ws = (char*)d_ws;
  u16* xb  = (u16*)ws;                                   // 1 MB
  u16* w1t = (u16*)(ws + (1u << 20));                    // 32 MB
  u16* w2t = (u16*)(ws + (1u << 20) + (32u << 20));      // 32 MB

  convert_x_k   <<<512,  256, 0, stream>>>(x,  xb);      // 512*256 == |x|/4 float4s
  transpose_w2_k<<<8192, 256, 0, stream>>>(W1, W2, w1t, w2t);
  rf_main_k     <<<4096, 512, 0, stream>>>(xb, w1t, w2t, b1, b2, W3, b3, out);
}

// Round 6
// 326.678 us; speedup vs baseline: 1.0884x; 1.0884x over previous
//
#include <hip/hip_runtime.h>

typedef unsigned short u16;
using u16x8  = __attribute__((ext_vector_type(8))) unsigned short;
using bf16x8 = __attribute__((ext_vector_type(8))) short;
using f32x16 = __attribute__((ext_vector_type(16))) float;

// ---------- helpers ----------
__device__ __forceinline__ u16 f2bf(float f) {
  union { float f; unsigned u; } v; v.f = f;
  unsigned r = v.u + 0x7FFFu + ((v.u >> 16) & 1u);  // RNE (inputs bounded, no NaN)
  return (u16)(r >> 16);
}

// ---------- pre-pass 1: x [2048][256] fp32 -> A-frag blocked bf16 ----------
// xA[(b>>5)][i>>4][b&31][i&15] : per 32x32x16 MFMA A-operand, dense 1KB wave loads.
// 65536 octets of 8 elems -> 256 blocks x 256 threads.
__global__ void convert_xA_k(const float* __restrict__ in, u16* __restrict__ out) {
  int flat = blockIdx.x * 256 + threadIdx.x;   // octet id
  int b   = flat >> 5;                         // batch row
  int oct = flat & 31;                         // i-octet (i = oct*8)
  const float4* src = (const float4*)(in + b * 256 + oct * 8);
  float4 v0 = src[0], v1 = src[1];
  u16x8 o;
  o[0] = f2bf(v0.x); o[1] = f2bf(v0.y); o[2] = f2bf(v0.z); o[3] = f2bf(v0.w);
  o[4] = f2bf(v1.x); o[5] = f2bf(v1.y); o[6] = f2bf(v1.z); o[7] = f2bf(v1.w);
  *(u16x8*)(out + ((b >> 5) << 13) + ((oct >> 1) << 9) + ((b & 31) << 4) + ((oct & 1) << 3)) = o;
}

// ---------- pre-pass 2: W [mat][i][h] fp32 -> blocked bf16 [mat][i/16][h][16] ----------
// element (k=i, n=h) at mat*65536 + (k>>4)*4096 + n*16 + (k&15)
__global__ __launch_bounds__(256) void transpose_w2_k(
    const float* __restrict__ W1, const float* __restrict__ W2,
    u16* __restrict__ w1t, u16* __restrict__ w2t) {
  __shared__ float tile[64][65];
  const int bid = blockIdx.x;
  const int mat = bid >> 4;
  const int tl  = bid & 15;
  const int i0 = (tl >> 2) * 64, h0 = (tl & 3) * 64;
  const float* src = (mat < 256) ? (W1 + mat * 65536) : (W2 + (mat - 256) * 65536);
  u16*       dst   = (mat < 256) ? (w1t + mat * 65536) : (w2t + (mat - 256) * 65536);
  const int t = threadIdx.x;
#pragma unroll
  for (int j = 0; j < 4; ++j) {
    int lin = j * 256 + t;
    int row = lin >> 4, c4 = lin & 15;
    float4 v = *(const float4*)(src + (i0 + row) * 256 + h0 + c4 * 4);
    tile[row][c4 * 4 + 0] = v.x; tile[row][c4 * 4 + 1] = v.y;
    tile[row][c4 * 4 + 2] = v.z; tile[row][c4 * 4 + 3] = v.w;
  }
  __syncthreads();
#pragma unroll
  for (int p = 0; p < 2; ++p) {
    int lin  = p * 256 + t;              // 512 octet-writes per tile
    int nloc = lin >> 3;                 // 0..63
    int oct  = lin & 7;                  // k-octet within 64 rows
    u16x8 o;
#pragma unroll
    for (int jj = 0; jj < 8; ++jj)
      o[jj] = f2bf(tile[oct * 8 + jj][nloc]);
    *(u16x8*)(dst + ((i0 >> 4) + (oct >> 1)) * 4096 + (h0 + nloc) * 16 + (oct & 1) * 8) = o;
  }
}

// ---------- main fused kernel ----------
// Block = (subcarrier c, 128-row batch tile). 512 threads = 8 waves, wave tile 64x64
// = 2x2 of mfma_f32_32x32x16_bf16. Phase A: A and B frags both DIRECT global->VGPR
// (dense 1KB/load, L2-resident via XCD-affine c mapping) -- no LDS, no barriers.
// H1 handoff through sH1 (stride 264); ONE barrier. Phase B: A from LDS, B global.
// LDS 67.6K + 2K red -> 2 blocks/CU = 16 waves/CU.
__global__ __launch_bounds__(512, 4) void rf_main_k(
    const u16* __restrict__ xA, const u16* __restrict__ w1t, const u16* __restrict__ w2t,
    const float* __restrict__ b1, const float* __restrict__ b2,
    const float* __restrict__ w3, const float* __restrict__ b3,
    float* __restrict__ out) {
  __shared__ u16 sH1[128 * 264];       // H1, padded stride 264
  __shared__ float red[512];           // 4 col-groups x 128 rows

  const int bid  = blockIdx.x;
  const int xcd  = bid & 7;
  const int j8   = bid >> 3;           // 0..511
  const int c    = xcd * 32 + (j8 >> 4);
  const int b0   = (j8 & 15) * 128;
  const int t    = threadIdx.x;
  const int lane = t & 63;
  const int w    = t >> 6;
  const int l31  = lane & 31;
  const int hi   = lane >> 5;          // k-octet select
  const int half = w >> 2;             // row half (0: rows 0-63, 1: rows 64-127)
  const int cb   = (w & 3) * 64;       // col base

  const u16* w1c = w1t + c * 65536;
  const u16* w2c = w2t + c * 65536;
  // dense per-lane offsets (u16 units)
  const int bBase = (cb + l31) * 16 + hi * 8;                    // + nt*512 + s*4096
  const int aBase = ((b0 >> 5) + half * 2) * 8192 + l31 * 16 + hi * 8;  // + mt*8192 + s*512
  const int aLds  = (half * 64 + l31) * 264 + hi * 8;            // + mt*32*264 + s*16

  f32x16 acc[2][2] = {};
  bf16x8 a0[2], a1[2], bb0[2], bb1[2];

#define LOADA(dst, s)                                             \
  { _Pragma("unroll")                                             \
    for (int _m = 0; _m < 2; ++_m)                                \
      dst[_m] = *(const bf16x8*)(xA + aBase + _m * 8192 + (s) * 512); }
#define LOADB(dst, wc, s)                                         \
  { _Pragma("unroll")                                             \
    for (int _n = 0; _n < 2; ++_n)                                \
      dst[_n] = *(const bf16x8*)((wc) + bBase + _n * 512 + (s) * 4096); }
#define COMP_G(AA, BB)                                            \
  { _Pragma("unroll")                                             \
    for (int _m = 0; _m < 2; ++_m)                                \
      _Pragma("unroll")                                           \
      for (int _n = 0; _n < 2; ++_n)                              \
        acc[_m][_n] = __builtin_amdgcn_mfma_f32_32x32x16_bf16(AA[_m], BB[_n], acc[_m][_n], 0, 0, 0); }
#define COMP_L(BB, s)                                             \
  { bf16x8 _a[2];                                                 \
    _Pragma("unroll")                                             \
    for (int _m = 0; _m < 2; ++_m)                                \
      _a[_m] = *(const bf16x8*)&sH1[aLds + _m * (32 * 264) + (s) * 16]; \
    _Pragma("unroll")                                             \
    for (int _m = 0; _m < 2; ++_m)                                \
      _Pragma("unroll")                                           \
      for (int _n = 0; _n < 2; ++_n)                              \
        acc[_m][_n] = __builtin_amdgcn_mfma_f32_32x32x16_bf16(_a[_m], BB[_n], acc[_m][_n], 0, 0, 0); }

  // ========== Phase A: H1 = relu(x @ W1[c] + b1): no LDS, no barriers ==========
  LOADA(a0, 0); LOADB(bb0, w1c, 0);
#pragma unroll 1
  for (int s = 0; s < 14; s += 2) {
    LOADA(a1, s + 1); LOADB(bb1, w1c, s + 1);
    COMP_G(a0, bb0);
    LOADA(a0, s + 2); LOADB(bb0, w1c, s + 2);
    COMP_G(a1, bb1);
  }
  LOADA(a1, 15); LOADB(bb1, w1c, 15);
  COMP_G(a0, bb0);
  LOADB(bb0, w2c, 0);                  // phase-B step-0 prefetch (global, pre-barrier OK)
  COMP_G(a1, bb1);

  // Phase A epilogue: bias+relu -> bf16 H1 (32x32 C-layout: col=lane&31,
  // row=(reg&3)+8*(reg>>2)+4*(lane>>5))
#pragma unroll
  for (int nt = 0; nt < 2; ++nt) {
    int col = cb + nt * 32 + l31;
    float bias = b1[c * 256 + col];
#pragma unroll
    for (int mt = 0; mt < 2; ++mt)
#pragma unroll
      for (int r = 0; r < 16; ++r) {
        int row = half * 64 + mt * 32 + (r & 3) + 8 * (r >> 2) + 4 * hi;
        float v = acc[mt][nt][r] + bias;
        v = v > 0.f ? v : 0.f;
        sH1[row * 264 + col] = f2bf(v);
        acc[mt][nt][r] = 0.f;
      }
  }
  __syncthreads();                     // H1 published (the only barrier before epilogue)

  // ========== Phase B: relu(H1 @ W2[c] + b2) . W3 ==========
#pragma unroll 1
  for (int s = 0; s < 14; s += 2) {
    LOADB(bb1, w2c, s + 1);
    COMP_L(bb0, s);
    LOADB(bb0, w2c, s + 2);
    COMP_L(bb1, s + 1);
  }
  LOADB(bb1, w2c, 15);
  COMP_L(bb0, 14);
  COMP_L(bb1, 15);

  // Phase B epilogue: out = relu(acc + b2) . W3 + b3
  float part[2][16];
#pragma unroll
  for (int mt = 0; mt < 2; ++mt)
#pragma unroll
    for (int r = 0; r < 16; ++r) part[mt][r] = 0.f;
#pragma unroll
  for (int nt = 0; nt < 2; ++nt) {
    int col = cb + nt * 32 + l31;
    float bias = b2[c * 256 + col];
    float w3v  = w3[c * 256 + col];
#pragma unroll
    for (int mt = 0; mt < 2; ++mt)
#pragma unroll
      for (int r = 0; r < 16; ++r) {
        float v = acc[mt][nt][r] + bias;
        v = v > 0.f ? v : 0.f;
        part[mt][r] += v * w3v;
      }
  }
  // reduce across the 32 lanes sharing each row set (low-5 lane bits)
#pragma unroll
  for (int m = 1; m < 32; m <<= 1)
#pragma unroll
    for (int mt = 0; mt < 2; ++mt)
#pragma unroll
      for (int r = 0; r < 16; ++r)
        part[mt][r] += __shfl_xor(part[mt][r], m, 64);

  if (l31 == 0) {                      // lanes 0 and 32 (hi=0/1) hold distinct rows
#pragma unroll
    for (int mt = 0; mt < 2; ++mt)
#pragma unroll
      for (int r = 0; r < 16; ++r) {
        int row = half * 64 + mt * 32 + (r & 3) + 8 * (r >> 2) + 4 * hi;
        red[(w & 3) * 128 + row] = part[mt][r];
      }
  }
  __syncthreads();
  if (t < 128) {
    float v = red[t] + red[128 + t] + red[256 + t] + red[384 + t] + b3[c];
    out[(b0 + t) * 256 + c] = v;
  }
#undef LOADA
#undef LOADB
#undef COMP_G
#undef COMP_L
}

// ---------- launcher ----------
extern "C" void kernel_launch(void* const* d_in, const int* in_sizes, int n_in,
                              void* d_out, int out_size, void* d_ws, size_t ws_size,
                              hipStream_t stream) {
  const float* x  = (const float*)d_in[0];
  const float* W1 = (const float*)d_in[1];
  const float* b1 = (const float*)d_in[2];
  const float* W2 = (const float*)d_in[3];
  const float* b2 = (const float*)d_in[4];
  const float* W3 = (const float*)d_in[5];
  const float* b3 = (const float*)d_in[6];
  float* out = (float*)d_out;

  char* ws = (char*)d_ws;
  u16* xA  = (u16*)ws;                                   // 1 MB
  u16* w1t = (u16*)(ws + (1u << 20));                    // 32 MB
  u16* w2t = (u16*)(ws + (1u << 20) + (32u << 20));      // 32 MB

  convert_xA_k  <<<256,  256, 0, stream>>>(x,  xA);      // 65536 octets
  transpose_w2_k<<<8192, 256, 0, stream>>>(W1, W2, w1t, w2t);
  rf_main_k     <<<4096, 512, 0, stream>>>(xA, w1t, w2t, b1, b2, W3, b3, out);
}

// Round 7
// 325.723 us; speedup vs baseline: 1.0916x; 1.0029x over previous
//
#include <hip/hip_runtime.h>

typedef unsigned short u16;
using u16x4  = __attribute__((ext_vector_type(4))) unsigned short;
using u16x8  = __attribute__((ext_vector_type(8))) unsigned short;
using bf16x8 = __attribute__((ext_vector_type(8))) short;
using f32x16 = __attribute__((ext_vector_type(16))) float;

// ---------- helpers ----------
__device__ __forceinline__ u16 f2bf(float f) {
  union { float f; unsigned u; } v; v.f = f;
  unsigned r = v.u + 0x7FFFu + ((v.u >> 16) & 1u);  // RNE (inputs bounded, no NaN)
  return (u16)(r >> 16);
}

// ---------- pre-pass 1: x fp32 -> bf16 row-major ----------
// x is 2048*256 fp32 = 131072 float4 -> EXACTLY 512 blocks of 256 threads.
__global__ void convert_x_k(const float* __restrict__ in, u16* __restrict__ out) {
  int i = blockIdx.x * 256 + threadIdx.x;
  float4 v = ((const float4*)in)[i];
  u16x4 u;
  u.x = f2bf(v.x); u.y = f2bf(v.y); u.z = f2bf(v.z); u.w = f2bf(v.w);
  ((u16x4*)out)[i] = u;
}

// ---------- pre-pass 2: W [mat][i][h] fp32 -> blocked bf16 [mat][i/16][h][16] ----------
// element (k=i, n=h) at mat*65536 + (k>>4)*4096 + n*16 + (k&15)
__global__ __launch_bounds__(256) void transpose_w2_k(
    const float* __restrict__ W1, const float* __restrict__ W2,
    u16* __restrict__ w1t, u16* __restrict__ w2t) {
  __shared__ float tile[64][65];
  const int bid = blockIdx.x;
  const int mat = bid >> 4;
  const int tl  = bid & 15;
  const int i0 = (tl >> 2) * 64, h0 = (tl & 3) * 64;
  const float* src = (mat < 256) ? (W1 + mat * 65536) : (W2 + (mat - 256) * 65536);
  u16*       dst   = (mat < 256) ? (w1t + mat * 65536) : (w2t + (mat - 256) * 65536);
  const int t = threadIdx.x;
#pragma unroll
  for (int j = 0; j < 4; ++j) {
    int lin = j * 256 + t;
    int row = lin >> 4, c4 = lin & 15;
    float4 v = *(const float4*)(src + (i0 + row) * 256 + h0 + c4 * 4);
    tile[row][c4 * 4 + 0] = v.x; tile[row][c4 * 4 + 1] = v.y;
    tile[row][c4 * 4 + 2] = v.z; tile[row][c4 * 4 + 3] = v.w;
  }
  __syncthreads();
#pragma unroll
  for (int p = 0; p < 2; ++p) {
    int lin  = p * 256 + t;              // 512 octet-writes per tile
    int nloc = lin >> 3;                 // 0..63
    int oct  = lin & 7;                  // k-octet within 64 rows
    u16x8 o;
#pragma unroll
    for (int jj = 0; jj < 8; ++jj)
      o[jj] = f2bf(tile[oct * 8 + jj][nloc]);
    *(u16x8*)(dst + ((i0 >> 4) + (oct >> 1)) * 4096 + (h0 + nloc) * 16 + (oct & 1) * 8) = o;
  }
}

// ---------- main fused kernel ----------
// Block = (c, 128-row batch tile). 512 thr = 8 waves, wave tile 64x64 = 2x2 of
// mfma_f32_32x32x16_bf16. A-frags from LDS (x staged once; H1 in place, stride 264 --
// 0-conflict pattern verified in r6). B-frags direct global->VGPR from L2-resident
// blocked W (XCD-affine c map), DEPTH-2 prefetch via 3 rotating buffers: >=2 load-sets
// in flight at every MFMA group. No barriers inside K-loops (3 total).
// LDS 69632 B -> 2 blocks/CU; regs ~128/thread -> 4 waves/SIMD.
__global__ __launch_bounds__(512, 4) void rf_main_k(
    const u16* __restrict__ xb, const u16* __restrict__ w1t, const u16* __restrict__ w2t,
    const float* __restrict__ b1, const float* __restrict__ b2,
    const float* __restrict__ w3, const float* __restrict__ b3,
    float* __restrict__ out) {
  __shared__ u16 sH[128 * 264];        // x, then H1 (in place), stride 264
  __shared__ float red[512];

  const int bid  = blockIdx.x;
  const int xcd  = bid & 7;
  const int j8   = bid >> 3;           // 0..511
  const int c    = xcd * 32 + (j8 >> 4);
  const int b0   = (j8 & 15) * 128;
  const int t    = threadIdx.x;
  const int lane = t & 63;
  const int w    = t >> 6;
  const int l31  = lane & 31;
  const int hi   = lane >> 5;          // k-octet select
  const int half = w >> 2;             // row half
  const int cb   = (w & 3) * 64;       // col base

  const u16* w1c = w1t + c * 65536;
  const u16* w2c = w2t + c * 65536;
  const int bBase = (cb + l31) * 16 + hi * 8;            // + nt*512 + s*4096
  const int aR    = (half * 64 + l31) * 264 + hi * 8;    // + mt*32*264 + s*16

  f32x16 acc[2][2] = {};
  bf16x8 a[2][2], bb[3][2];

#define BL(i, wc, s)                                                     \
  { bb[i][0] = *(const bf16x8*)((wc) + bBase + (s) * 4096);              \
    bb[i][1] = *(const bf16x8*)((wc) + bBase + 512 + (s) * 4096); }
#define AL(ai, s)                                                        \
  { a[ai][0] = *(const bf16x8*)&sH[aR + (s) * 16];                       \
    a[ai][1] = *(const bf16x8*)&sH[aR + 32 * 264 + (s) * 16]; }
#define MM(ai, bi)                                                       \
  { _Pragma("unroll")                                                    \
    for (int _m = 0; _m < 2; ++_m)                                       \
      _Pragma("unroll")                                                  \
      for (int _n = 0; _n < 2; ++_n)                                     \
        acc[_m][_n] = __builtin_amdgcn_mfma_f32_32x32x16_bf16(           \
            a[ai][_m], bb[bi][_n], acc[_m][_n], 0, 0, 0); }

  // B prefetch (steps 0,1) issued before x staging
  BL(0, w1c, 0); BL(1, w1c, 1);

  // stage x-tile: 128 rows x 256 u16 -> sH stride 264
#pragma unroll
  for (int i = 0; i < 8; ++i) {
    int flat = i * 512 + t;
    int r = flat >> 5, s = flat & 31;
    *(u16x8*)&sH[r * 264 + s * 8] = *(const u16x8*)(xb + (b0 + r) * 256 + s * 8);
  }
  __syncthreads();

  // ===== Phase A: H1 = relu(x @ W1[c] + b1). step s: BL((s+2)%3,s+2); AL((s+1)&1,s+1); MM(s&1,s%3)
  AL(0, 0);
  BL(2, w1c, 2);  AL(1, 1);  MM(0, 0);
  BL(0, w1c, 3);  AL(0, 2);  MM(1, 1);
  BL(1, w1c, 4);  AL(1, 3);  MM(0, 2);
  BL(2, w1c, 5);  AL(0, 4);  MM(1, 0);
  BL(0, w1c, 6);  AL(1, 5);  MM(0, 1);
  BL(1, w1c, 7);  AL(0, 6);  MM(1, 2);
  BL(2, w1c, 8);  AL(1, 7);  MM(0, 0);
  BL(0, w1c, 9);  AL(0, 8);  MM(1, 1);
  BL(1, w1c, 10); AL(1, 9);  MM(0, 2);
  BL(2, w1c, 11); AL(0, 10); MM(1, 0);
  BL(0, w1c, 12); AL(1, 11); MM(0, 1);
  BL(1, w1c, 13); AL(0, 12); MM(1, 2);
  BL(2, w1c, 14); AL(1, 13); MM(0, 0);
  BL(0, w1c, 15); AL(0, 14); MM(1, 1);
  BL(1, w2c, 0);  AL(1, 15); MM(0, 2);   // tail prefetch: phase-B step 0 -> buf 1
  BL(2, w2c, 1);             MM(1, 0);   // phase-B step 1 -> buf 2

  // Phase A epilogue: bias+relu -> bf16 H1 in place (C-layout: col=lane&31,
  // row=(r&3)+8*(r>>2)+4*hi)
  __syncthreads();                       // all x reads retired
#pragma unroll
  for (int nt = 0; nt < 2; ++nt) {
    int col = cb + nt * 32 + l31;
    float bias = b1[c * 256 + col];
#pragma unroll
    for (int mt = 0; mt < 2; ++mt)
#pragma unroll
      for (int r = 0; r < 16; ++r) {
        int row = half * 64 + mt * 32 + (r & 3) + 8 * (r >> 2) + 4 * hi;
        float v = acc[mt][nt][r] + bias;
        v = v > 0.f ? v : 0.f;
        sH[row * 264 + col] = f2bf(v);
        acc[mt][nt][r] = 0.f;
      }
  }
  __syncthreads();                       // H1 published

  // ===== Phase B: relu(H1 @ W2[c] + b2) . W3. step t: BL(t%3,t+2); AL((t+1)&1,t+1); MM(t&1,(t+1)%3)
  AL(0, 0);
  BL(0, w2c, 2);  AL(1, 1);  MM(0, 1);
  BL(1, w2c, 3);  AL(0, 2);  MM(1, 2);
  BL(2, w2c, 4);  AL(1, 3);  MM(0, 0);
  BL(0, w2c, 5);  AL(0, 4);  MM(1, 1);
  BL(1, w2c, 6);  AL(1, 5);  MM(0, 2);
  BL(2, w2c, 7);  AL(0, 6);  MM(1, 0);
  BL(0, w2c, 8);  AL(1, 7);  MM(0, 1);
  BL(1, w2c, 9);  AL(0, 8);  MM(1, 2);
  BL(2, w2c, 10); AL(1, 9);  MM(0, 0);
  BL(0, w2c, 11); AL(0, 10); MM(1, 1);
  BL(1, w2c, 12); AL(1, 11); MM(0, 2);
  BL(2, w2c, 13); AL(0, 12); MM(1, 0);
  BL(0, w2c, 14); AL(1, 13); MM(0, 1);
  BL(1, w2c, 15); AL(0, 14); MM(1, 2);
                  AL(1, 15); MM(0, 0);
                             MM(1, 1);

  // Phase B epilogue: out = relu(acc + b2) . W3 + b3
  float part[2][16];
#pragma unroll
  for (int mt = 0; mt < 2; ++mt)
#pragma unroll
    for (int r = 0; r < 16; ++r) part[mt][r] = 0.f;
#pragma unroll
  for (int nt = 0; nt < 2; ++nt) {
    int col = cb + nt * 32 + l31;
    float bias = b2[c * 256 + col];
    float w3v  = w3[c * 256 + col];
#pragma unroll
    for (int mt = 0; mt < 2; ++mt)
#pragma unroll
      for (int r = 0; r < 16; ++r) {
        float v = acc[mt][nt][r] + bias;
        v = v > 0.f ? v : 0.f;
        part[mt][r] += v * w3v;
      }
  }
#pragma unroll
  for (int m = 1; m < 32; m <<= 1)
#pragma unroll
    for (int mt = 0; mt < 2; ++mt)
#pragma unroll
      for (int r = 0; r < 16; ++r)
        part[mt][r] += __shfl_xor(part[mt][r], m, 64);

  if (l31 == 0) {
#pragma unroll
    for (int mt = 0; mt < 2; ++mt)
#pragma unroll
      for (int r = 0; r < 16; ++r) {
        int row = half * 64 + mt * 32 + (r & 3) + 8 * (r >> 2) + 4 * hi;
        red[(w & 3) * 128 + row] = part[mt][r];
      }
  }
  __syncthreads();
  if (t < 128) {
    float v = red[t] + red[128 + t] + red[256 + t] + red[384 + t] + b3[c];
    out[(b0 + t) * 256 + c] = v;
  }
#undef BL
#undef AL
#undef MM
}

// ---------- launcher ----------
extern "C" void kernel_launch(void* const* d_in, const int* in_sizes, int n_in,
                              void* d_out, int out_size, void* d_ws, size_t ws_size,
                              hipStream_t stream) {
  const float* x  = (const float*)d_in[0];
  const float* W1 = (const float*)d_in[1];
  const float* b1 = (const float*)d_in[2];
  const float* W2 = (const float*)d_in[3];
  const float* b2 = (const float*)d_in[4];
  const float* W3 = (const float*)d_in[5];
  const float* b3 = (const float*)d_in[6];
  float* out = (float*)d_out;

  char* ws = (char*)d_ws;
  u16* xb  = (u16*)ws;                                   // 1 MB
  u16* w1t = (u16*)(ws + (1u << 20));                    // 32 MB
  u16* w2t = (u16*)(ws + (1u << 20) + (32u << 20));      // 32 MB

  convert_x_k   <<<512,  256, 0, stream>>>(x,  xb);      // 512*256 == |x|/4 float4s
  transpose_w2_k<<<8192, 256, 0, stream>>>(W1, W2, w1t, w2t);
  rf_main_k     <<<4096, 512, 0, stream>>>(xb, w1t, w2t, b1, b2, W3, b3, out);
}